// Round 6
// baseline (142.413 us; speedup 1.0000x reference)
//
#include <hip/hip_runtime.h>
#include <math.h>

// Single-head causal attention, MFMA bf16 pipeline (R15 = R10 + row compaction).
//   x:[8,2048,1024] f32, Wq/Wk/Wv:[1024,64] f32, zero_mask:[8,2048] i32
//   out:[8,2048,64] f32
// KEY INSIGHT: zero_mask kills ~50% of query rows POST-softmax -> their whole
// QK^T/softmax/PV chain is dead work. scan_kernel compacts unmasked row
// indices per batch (idx[b][.], cnt[b]) and zero-fills masked output rows.
// attn operates on COMPACTED q-tiles: tile jt covers original rows ~2x its
// index, so total key-tile iterations drop ~48% (272 vs 528 per batch).
// Causal mask applied EVERY tile from per-row original indices.
//
// wcvt: Wt[192][1024] bf16 (B-operand layout)                       [R10]
// qkv : 512 blocks x 256 thr, 32 rows x 192 cols, single X pass.    [R10]
// attn: R10 schedule (4 waves, dbuf K/V swizzled DMA, Ps stride-88,
//       split-K chunk 8) on compacted rows. Grid (8,18,4), early-exit.
// comb: compacted rows in tiles with nkt>8 sum ns partials, write to
//       out[idx[crow]]. No zmask anywhere downstream of scan.
//
// MFMA 16x16x32 layouts (HW-verified):
//   A[m][k]: m = lane&15, k = (lane>>4)*8 + j
//   B[k][n]: n = lane&15, k = (lane>>4)*8 + j
//   C/D:     col = lane&15, row = (lane>>4)*4 + reg
//
// Swizzles (reader applies same XOR as the DMA source permutation):
//   W row (64 bf16 = 8 granules):  slot = g ^ (nloc & 7)
//   X row (64 fp32 = 16 granules): slot = g ^ (row & 15)

#define B_ 8
#define C_ 2048
#define E_ 1024
#define H_ 64
// 2048^-0.5 * log2(e): scores are computed in the log2 domain -> v_exp_f32
#define SCALE (0.02209708691207961f * 1.4426950408889634f)
#define NCMAX 1152   // compacted-row capacity (1024 + 5.7 sigma headroom)

typedef __attribute__((ext_vector_type(8))) short short8;
typedef __attribute__((ext_vector_type(4))) float floatx4;

union BF8 { short8 s8; unsigned int u[4]; };

static __device__ __forceinline__ unsigned int pack_bf2(float lo, float hi) {
    unsigned int a = __builtin_bit_cast(unsigned int, lo);
    unsigned int b = __builtin_bit_cast(unsigned int, hi);
    return (a >> 16) | (b & 0xFFFF0000u);
}
static __device__ __forceinline__ unsigned short f2bf(float f) {
    return (unsigned short)(__builtin_bit_cast(unsigned int, f) >> 16);
}
static __device__ __forceinline__ void load_lds16(const void* g, void* l) {
    __builtin_amdgcn_global_load_lds(
        (const __attribute__((address_space(1))) void*)g,
        (__attribute__((address_space(3))) void*)l, 16, 0, 0);
}

// ---------------------------------------------------------------------------
// scan: per batch, compact unmasked row indices; zero-fill masked out rows.
// 8 blocks x 256 thr; thread t owns rows t*8..t*8+7.
// ---------------------------------------------------------------------------
__global__ __launch_bounds__(256) void scan_kernel(
    const int* __restrict__ zmask, float* __restrict__ out,
    int* __restrict__ idx, int* __restrict__ cnt)
{
    __shared__ int wsum[4];
    const int b = (int)blockIdx.x;
    const int t = (int)threadIdx.x;
    const int lane = t & 63, w = t >> 6;
    const int r0 = t * 8;
    int f[8];
    int s = 0;
#pragma unroll
    for (int j = 0; j < 8; j++) {
        f[j] = (zmask[b * C_ + r0 + j] == 0) ? 1 : 0;
        s += f[j];
    }
    int v = s;   // wave-inclusive scan
#pragma unroll
    for (int d = 1; d < 64; d <<= 1) {
        int u = __shfl_up(v, d);
        if (lane >= d) v += u;
    }
    if (lane == 63) wsum[w] = v;
    __syncthreads();
    int base = 0;
    for (int i = 0; i < w; i++) base += wsum[i];
    int ex = base + v - s;          // exclusive prefix for this thread
    if (t == 255) cnt[b] = base + v;
#pragma unroll
    for (int j = 0; j < 8; j++) {
        const int row = r0 + j;
        if (f[j]) {
            idx[b * C_ + ex] = row;
            ex++;
        } else {
            float* o = out + (size_t)(b * C_ + row) * 64;
            const float4 z4 = make_float4(0.f, 0.f, 0.f, 0.f);
#pragma unroll
            for (int q = 0; q < 16; q++) *(float4*)(o + q * 4) = z4;
        }
    }
}

// ---------------------------------------------------------------------------
// Wt[n=192][k=1024] bf16 from Wq/Wk/Wv[k][64] f32. 48 blocks.   [R10 verbatim]
// ---------------------------------------------------------------------------
__global__ __launch_bounds__(256) void wcvt_kernel(
    const float* __restrict__ Wq, const float* __restrict__ Wk,
    const float* __restrict__ Wv, unsigned short* __restrict__ wt)
{
    __shared__ float lds[64][68];
    const int bid = (int)blockIdx.x;
    const int m = bid >> 4, kt = bid & 15, k0 = kt * 64;
    const float* W = (m == 0) ? Wq : (m == 1) ? Wk : Wv;
    const int t = (int)threadIdx.x;
#pragma unroll
    for (int j = 0; j < 4; j++) {
        int idx4 = j * 256 + t;
        int row = idx4 >> 4, c4 = idx4 & 15;
        float4 v = *(const float4*)(W + (size_t)(k0 + row) * 64 + c4 * 4);
        *(float4*)&lds[row][c4 * 4] = v;
    }
    __syncthreads();
#pragma unroll
    for (int j = 0; j < 2; j++) {
        int g = j * 256 + t;
        int n = g >> 3, kk = (g & 7) * 8;
        unsigned int o[4];
#pragma unroll
        for (int i = 0; i < 4; i++)
            o[i] = pack_bf2(lds[kk + 2 * i][n], lds[kk + 2 * i + 1][n]);
        *(uint4*)(wt + (size_t)(m * 64 + n) * 1024 + k0 + kk) =
            make_uint4(o[0], o[1], o[2], o[3]);
    }
}

// ---------------------------------------------------------------------------
// QKV: M=16384, N=192, K=1024. Grid (512 rowtiles), 256 thr.   [R10 verbatim]
// ---------------------------------------------------------------------------
__global__ __launch_bounds__(256, 2) void qkv_kernel(
    const float* __restrict__ X, const unsigned short* __restrict__ wt,
    unsigned short* __restrict__ qg, unsigned short* __restrict__ kg,
    unsigned short* __restrict__ vtile)
{
    // layout: X dbuf 2x8 KB | W dbuf 2x24 KB
    __shared__ __align__(16) unsigned char smem[2 * 8192 + 2 * 24576];
    unsigned short* vstage = (unsigned short*)smem;   // 5 KB alias, post-loop

    const int t = (int)threadIdx.x;
    const int w = t >> 6, lane = t & 63;
    const int l15 = lane & 15, quad = lane >> 4;
    const int r0 = (int)blockIdx.x * 32;
    const int rbase = (w & 1) * 16;
    const int nloc0 = (w >> 1) * 96;

    const int wrow_off = lane >> 3, wgs = lane & 7;

    floatx4 acc[6];
#pragma unroll
    for (int j = 0; j < 6; j++) acc[j] = (floatx4){0.f, 0.f, 0.f, 0.f};

#define XBUF(q) (smem + (q) * 8192)
#define WBUF(q) (smem + 16384 + (q) * 24576)
#define STAGE_X(c, q) do {                                                   \
        _Pragma("unroll")                                                    \
        for (int j = 0; j < 2; j++) {                                        \
            const int gi = w * 128 + j * 64 + lane;                          \
            const int row = gi >> 4;                                         \
            const int g = (gi & 15) ^ (row & 15);                            \
            load_lds16(X + (size_t)(r0 + row) * E_ + (c) * 64 + g * 4,       \
                       XBUF(q) + (w * 128 + j * 64) * 16);                   \
        }                                                                    \
    } while (0)
#define STAGE_W(c, q) do {                                                   \
        _Pragma("unroll")                                                    \
        for (int j = 0; j < 6; j++) {                                        \
            const int region = w * 6 + j;                                    \
            const int nloc = region * 8 + wrow_off;                          \
            const int gsrc = wgs ^ (nloc & 7);                               \
            load_lds16(wt + (size_t)nloc * 1024 + (c) * 64 + gsrc * 8,       \
                       WBUF(q) + region * 1024);                             \
        }                                                                    \
    } while (0)

    STAGE_X(0, 0);
    STAGE_W(0, 0);

#pragma unroll
    for (int c = 0; c < 16; c++) {
        __syncthreads();   // drains DMA issued last iter (vmcnt(0) structural)
        if (c + 1 < 16) {
            STAGE_X(c + 1, (c + 1) & 1);
            STAGE_W(c + 1, (c + 1) & 1);
        }
        const float4* xc = (const float4*)XBUF(c & 1);
        const unsigned short* wc = (const unsigned short*)WBUF(c & 1);

#pragma unroll
        for (int ks = 0; ks < 2; ks++) {
            const int g0 = ks * 8 + quad * 2;
            const float4* xrow = xc + (rbase + l15) * 16;
            float4 f0 = xrow[g0 ^ l15];
            float4 f1 = xrow[(g0 + 1) ^ l15];
            BF8 a;
            a.u[0] = pack_bf2(f0.x, f0.y);
            a.u[1] = pack_bf2(f0.z, f0.w);
            a.u[2] = pack_bf2(f1.x, f1.y);
            a.u[3] = pack_bf2(f1.z, f1.w);
#pragma unroll
            for (int nt = 0; nt < 6; nt++) {
                const int nloc = nloc0 + nt * 16 + l15;
                const int slot = (ks * 4 + quad) ^ (nloc & 7);
                short8 bfr = *(const short8*)(wc + nloc * 64 + slot * 8);
                acc[nt] = __builtin_amdgcn_mfma_f32_16x16x32_bf16(
                    a.s8, bfr, acc[nt], 0, 0, 0);
            }
        }
    }
#undef STAGE_X
#undef STAGE_W
#undef XBUF
#undef WBUF

    const int bb = r0 >> 11;
    const int keybase = r0 & 2047;
    const int rowl0 = rbase + quad * 4;
    __syncthreads();   // all LDS reads done; safe to alias vstage
#pragma unroll
    for (int nt = 0; nt < 6; nt++) {
        const int n = nloc0 + nt * 16 + l15;
        if (n < 64) {
#pragma unroll
            for (int r = 0; r < 4; r++)
                qg[(size_t)(r0 + rowl0 + r) * 64 + n] = f2bf(acc[nt][r] * SCALE);
        } else if (n < 128) {
#pragma unroll
            for (int r = 0; r < 4; r++)
                kg[(size_t)(r0 + rowl0 + r) * 64 + (n - 64)] = f2bf(acc[nt][r]);
        } else {
            const int h = n - 128;
            *(unsigned int*)&vstage[h * 40 + rowl0] =
                pack_bf2(acc[nt][0], acc[nt][1]);
            *(unsigned int*)&vstage[h * 40 + rowl0 + 2] =
                pack_bf2(acc[nt][2], acc[nt][3]);
        }
    }
    __syncthreads();
    {
        const int h = t >> 2, part = t & 3;
        uint4 v = *(const uint4*)&vstage[h * 40 + part * 8];
        *(uint4*)(vtile + ((size_t)(bb * 32 + (keybase >> 6)) * 64 + h) * 64
                  + (keybase & 63) + part * 8) = v;
    }
}

// ---------------------------------------------------------------------------
// Attention on COMPACTED rows. Grid (8, 18, 4); 256 thr; 64 compacted
// q-rows/block. Split z covers key-tiles [8z, min(8z+8,nkt)), nkt from the
// tile's max ORIGINAL row. Causal predicate every tile (per-row orig index).
// ns==1: direct normalized out[idx[..]]. Else partials indexed by crow.
// ---------------------------------------------------------------------------
__global__ __launch_bounds__(256, 3) void attn_kernel(
    const unsigned short* __restrict__ qg, const unsigned short* __restrict__ kg,
    const unsigned short* __restrict__ vtile,
    const int* __restrict__ idx, const int* __restrict__ cnt,
    float* __restrict__ opart, float* __restrict__ lpart,
    float* __restrict__ out)
{
    __shared__ unsigned short Klds[2][64 * 64];  // swizzled [key][64h]
    __shared__ unsigned short Vlds[2][64 * 64];  // swizzled [h][64key]
    __shared__ unsigned short Ps[64 * 88];       // per-wave-private rows

    const int t = (int)threadIdx.x;
    const int w = t >> 6, lane = t & 63;
    const int l15 = lane & 15, quad = lane >> 4;
    const int b = (int)blockIdx.x;
    const int jt = (int)blockIdx.y;            // compacted 64-row tile
    const int z = (int)blockIdx.z;
    const int cntb = cnt[b];
    const int q0c = jt * 64;
    if (q0c >= cntb) return;
    const int last = (q0c + 63 < cntb - 1) ? (q0c + 63) : (cntb - 1);
    const int rmax = idx[b * C_ + last];
    const int nkt = (rmax >> 6) + 1;           // key-tiles needed for tile
    const int t0 = z * 8;
    const int t1 = (t0 + 8 < nkt) ? (t0 + 8) : nkt;
    if (t0 >= t1) return;
    const int ns = (nkt + 7) >> 3;

    const int srow_off = lane >> 3, sgs = lane & 7;

    // per-lane compacted->original row for the Q gather (A rows = l15)
    const int qcl0 = q0c + w * 16 + l15;
    const int qcl = (qcl0 < cntb - 1) ? qcl0 : (cntb - 1);
    const int qrow = idx[b * C_ + qcl];
    short8 qfr[2];
#pragma unroll
    for (int kc = 0; kc < 2; kc++)
        qfr[kc] = *(const short8*)(qg + ((size_t)b * C_ + qrow) * 64
                                   + kc * 32 + quad * 8);

    // per-accumulator-row original index + validity (C/D rows = quad*4+r)
    int orow[4], vld[4];
#pragma unroll
    for (int r = 0; r < 4; r++) {
        const int cr0 = q0c + w * 16 + quad * 4 + r;
        vld[r] = (cr0 < cntb) ? 1 : 0;
        const int cr = vld[r] ? cr0 : (cntb - 1);
        orow[r] = idx[b * C_ + cr];
    }

    floatx4 accO[4];
#pragma unroll
    for (int i = 0; i < 4; i++) accO[i] = (floatx4){0.f, 0.f, 0.f, 0.f};
    float lsum[4] = {0.f, 0.f, 0.f, 0.f};

    // stage tile t0 into buf 0 (8 regions of 8 rows; wave w: regions 2w,2w+1)
#pragma unroll
    for (int j = 0; j < 2; j++) {
        const int region = w * 2 + j;
        const int row = region * 8 + srow_off;
        const int gsrc = sgs ^ (row & 7);
        load_lds16(kg + ((size_t)b * C_ + t0 * 64 + row) * 64 + gsrc * 8,
                   &Klds[0][region * 512]);
        load_lds16(vtile + (((size_t)b * 32 + t0) * 64 + row) * 64 + gsrc * 8,
                   &Vlds[0][region * 512]);
    }

    int buf = 0;
    for (int kt = t0; kt < t1; kt++) {
        __syncthreads();
        if (kt + 1 < t1) {
            const int k0n = (kt + 1) * 64;
#pragma unroll
            for (int j = 0; j < 2; j++) {
                const int region = w * 2 + j;
                const int row = region * 8 + srow_off;
                const int gsrc = sgs ^ (row & 7);
                load_lds16(kg + ((size_t)b * C_ + k0n + row) * 64 + gsrc * 8,
                           &Klds[buf ^ 1][region * 512]);
                load_lds16(vtile + (((size_t)b * 32 + kt + 1) * 64 + row) * 64 + gsrc * 8,
                           &Vlds[buf ^ 1][region * 512]);
            }
        }

        floatx4 s[4];
#pragma unroll
        for (int nt = 0; nt < 4; nt++) {
            const int row = nt * 16 + l15;
            short8 kf0 = *(const short8*)&Klds[buf][row * 64 + ((quad) ^ (row & 7)) * 8];
            short8 kf1 = *(const short8*)&Klds[buf][row * 64 + ((4 + quad) ^ (row & 7)) * 8];
            floatx4 zz = (floatx4){0.f, 0.f, 0.f, 0.f};
            zz = __builtin_amdgcn_mfma_f32_16x16x32_bf16(qfr[0], kf0, zz, 0, 0, 0);
            s[nt] = __builtin_amdgcn_mfma_f32_16x16x32_bf16(qfr[1], kf1, zz, 0, 0, 0);
        }
        float pr[4][4];
#pragma unroll
        for (int nt = 0; nt < 4; nt++)
#pragma unroll
            for (int r = 0; r < 4; r++)
                pr[nt][r] = __builtin_amdgcn_exp2f(s[nt][r]);
        // causal predicate EVERY tile: compacted tiles straddle the diagonal
        {
            const int k0 = kt * 64;
#pragma unroll
            for (int nt = 0; nt < 4; nt++) {
                const int key = k0 + nt * 16 + l15;
#pragma unroll
                for (int r = 0; r < 4; r++)
                    if (key > orow[r]) pr[nt][r] = 0.f;
            }
        }
#pragma unroll
        for (int nt = 0; nt < 4; nt++)
#pragma unroll
            for (int r = 0; r < 4; r++) {
                lsum[r] += pr[nt][r];
                Ps[(w * 16 + quad * 4 + r) * 88 + nt * 16 + l15] = f2bf(pr[nt][r]);
            }
#pragma unroll
        for (int kc = 0; kc < 2; kc++) {
            short8 af = *(const short8*)&Ps[(w * 16 + l15) * 88 + kc * 32 + quad * 8];
#pragma unroll
            for (int nt = 0; nt < 4; nt++) {
                const int row = nt * 16 + l15;
                short8 vf = *(const short8*)&Vlds[buf][row * 64
                                + ((kc * 4 + quad) ^ (row & 7)) * 8];
                accO[nt] = __builtin_amdgcn_mfma_f32_16x16x32_bf16(
                    af, vf, accO[nt], 0, 0, 0);
            }
        }
        buf ^= 1;
    }

    // reduce l across the 16 col-lanes
#pragma unroll
    for (int r = 0; r < 4; r++) {
        float v = lsum[r];
        v += __shfl_xor(v, 1);
        v += __shfl_xor(v, 2);
        v += __shfl_xor(v, 4);
        v += __shfl_xor(v, 8);
        lsum[r] = v;
    }

    if (ns == 1) {
        float inv[4];
#pragma unroll
        for (int r = 0; r < 4; r++)
            inv[r] = 1.0f / lsum[r];
#pragma unroll
        for (int nt = 0; nt < 4; nt++)
#pragma unroll
            for (int r = 0; r < 4; r++)
                if (vld[r])
                    out[(size_t)(b * C_ + orow[r]) * 64 + nt * 16 + l15] =
                        accO[nt][r] * inv[r];
    } else {
        // partials indexed by compacted row: opart[z][b][crow][h]
        const int lrow = q0c + w * 16 + quad * 4;
        float* ob = opart + ((size_t)(z * 8 + b) * NCMAX + lrow) * 64;
#pragma unroll
        for (int nt = 0; nt < 4; nt++)
#pragma unroll
            for (int r = 0; r < 4; r++)
                ob[(size_t)r * 64 + nt * 16 + l15] = accO[nt][r];
        if (l15 == 0) {
#pragma unroll
            for (int r = 0; r < 4; r++)
                lpart[(size_t)(z * 8 + b) * NCMAX + lrow + r] = lsum[r];
        }
    }
}

// ---------------------------------------------------------------------------
// Combine compacted rows whose tile has nkt > 8: out[idx[crow]] = SUM/sum_l.
// Grid (72, 8): 8 b x 1152 crows x 16 float4.
// ---------------------------------------------------------------------------
__global__ __launch_bounds__(256) void combine_kernel(
    const float* __restrict__ opart, const float* __restrict__ lpart,
    const int* __restrict__ idx, const int* __restrict__ cnt,
    float* __restrict__ out)
{
    const int b = (int)blockIdx.y;
    const int gid = (int)blockIdx.x * 256 + (int)threadIdx.x;  // 0..18431
    const int crow = gid >> 4;         // 0..1151
    const int f4 = gid & 15;
    const int cntb = cnt[b];
    if (crow >= cntb) return;
    const int jt = crow >> 6;
    const int last = (jt * 64 + 63 < cntb - 1) ? (jt * 64 + 63) : (cntb - 1);
    const int rmax = idx[b * C_ + last];
    const int nkt = (rmax >> 6) + 1;
    const int ns = (nkt + 7) >> 3;
    if (ns < 2) return;                // direct-written by attn

    float4 o = make_float4(0.f, 0.f, 0.f, 0.f);
    float l = 0.f;
    for (int zc = 0; zc < ns; zc++) {
        float4 p = *(const float4*)(opart
            + ((size_t)(zc * 8 + b) * NCMAX + crow) * 64 + f4 * 4);
        o.x += p.x; o.y += p.y; o.z += p.z; o.w += p.w;
        l += lpart[(size_t)(zc * 8 + b) * NCMAX + crow];
    }
    const float inv = 1.0f / l;
    const int orig = idx[b * C_ + crow];
    *(float4*)(out + (size_t)(b * C_ + orig) * 64 + f4 * 4) =
        make_float4(o.x * inv, o.y * inv, o.z * inv, o.w * inv);
}

// ---------------------------------------------------------------------------
extern "C" void kernel_launch(void* const* d_in, const int* in_sizes, int n_in,
                              void* d_out, int out_size, void* d_ws, size_t ws_size,
                              hipStream_t stream) {
    const float* X  = (const float*)d_in[0];
    const float* Wq = (const float*)d_in[1];
    const float* Wk = (const float*)d_in[2];
    const float* Wv = (const float*)d_in[3];
    const int*   zm = (const int*)d_in[4];
    float* out = (float*)d_out;

    unsigned short* qg    = (unsigned short*)d_ws;               // 2 MB
    unsigned short* kg    = qg    + (size_t)B_ * C_ * H_;        // 2 MB
    unsigned short* vtile = kg    + (size_t)B_ * C_ * H_;        // 2 MB
    unsigned short* wt    = vtile + (size_t)B_ * C_ * H_;        // 384 KB
    int* idx = (int*)(wt + (size_t)192 * 1024);                  // 64 KB
    int* cnt = idx + (size_t)B_ * C_;                            // 64 B (padded)
    float* opart = (float*)(cnt + 16);                           // 9 MB
    float* lpart = opart + (size_t)4 * B_ * NCMAX * 64;          // 147 KB

    scan_kernel<<<dim3(B_), dim3(256), 0, stream>>>(zm, out, idx, cnt);
    wcvt_kernel<<<dim3(48), dim3(256), 0, stream>>>(Wq, Wk, Wv, wt);
    qkv_kernel<<<dim3(512), dim3(256), 0, stream>>>(X, wt, qg, kg, vtile);
    attn_kernel<<<dim3(B_, 18, 4), dim3(256), 0, stream>>>(
        qg, kg, vtile, idx, cnt, opart, lpart, out);
    combine_kernel<<<dim3(72, B_), dim3(256), 0, stream>>>(
        opart, lpart, idx, cnt, out);
}

// Round 7
// 134.786 us; speedup vs baseline: 1.0566x; 1.0566x over previous
//
#include <hip/hip_runtime.h>
#include <math.h>

// Single-head causal attention, MFMA bf16 pipeline (R16 = R10 + 8-wave qkv).
//   x:[8,2048,1024] f32, Wq/Wk/Wv:[1024,64] f32, zero_mask:[8,2048] i32
//   out:[8,2048,64] f32
// R15 post-mortem: qkv_kernel surfaced at 42 us with MfmaUtil 5%, VALUBusy 5%,
// HBM 12%, Occupancy 19.75% -> pure latency/convoy bound at 2 waves/SIMD.
// R16: qkv goes 256 -> 512 threads (8 waves), same 32x192 block, same 64 KB
// LDS, same grid: per-wave work halves, waves/SIMD doubles (2 -> 4) to
// overlap ds_read chains + DMA drains. Row compaction (R15) reverted.
//
// wcvt: Wt[192][1024] bf16 (B-operand layout)                       [R10]
// qkv : 512 blocks x 512 thr, 32 rows x 192 cols, single X pass.
//       Wave w: rows (w&1)*16, n-tiles (w>>1)*3 (48 cols). X dbuf 16 KB +
//       W dbuf 48 KB = 64 KB -> 2 blocks/CU = 4 waves/SIMD.
// attn: R10 verbatim (64 q-rows, 4 waves, dbuf K/V swizzled DMA, Ps
//       stride-88, split-K chunk 8, grid (8,32,4), 3 blocks/CU).
// comb: rows >= 512 sum ns=ceil(nkt/8) in {2..4} partials.          [R10]
//
// MFMA 16x16x32 layouts (HW-verified):
//   A[m][k]: m = lane&15, k = (lane>>4)*8 + j
//   B[k][n]: n = lane&15, k = (lane>>4)*8 + j
//   C/D:     col = lane&15, row = (lane>>4)*4 + reg
//
// Swizzles (reader applies same XOR as the DMA source permutation):
//   W row (64 bf16 = 8 granules):  slot = g ^ (nloc & 7)
//   X row (64 fp32 = 16 granules): slot = g ^ (row & 15)

#define B_ 8
#define C_ 2048
#define E_ 1024
#define H_ 64
// 2048^-0.5 * log2(e): scores are computed in the log2 domain -> v_exp_f32
#define SCALE (0.02209708691207961f * 1.4426950408889634f)

typedef __attribute__((ext_vector_type(8))) short short8;
typedef __attribute__((ext_vector_type(4))) float floatx4;

union BF8 { short8 s8; unsigned int u[4]; };

static __device__ __forceinline__ unsigned int pack_bf2(float lo, float hi) {
    unsigned int a = __builtin_bit_cast(unsigned int, lo);
    unsigned int b = __builtin_bit_cast(unsigned int, hi);
    return (a >> 16) | (b & 0xFFFF0000u);
}
static __device__ __forceinline__ unsigned short f2bf(float f) {
    return (unsigned short)(__builtin_bit_cast(unsigned int, f) >> 16);
}
static __device__ __forceinline__ void load_lds16(const void* g, void* l) {
    __builtin_amdgcn_global_load_lds(
        (const __attribute__((address_space(1))) void*)g,
        (__attribute__((address_space(3))) void*)l, 16, 0, 0);
}

// ---------------------------------------------------------------------------
// Wt[n=192][k=1024] bf16 from Wq/Wk/Wv[k][64] f32. 48 blocks.   [R10 verbatim]
// ---------------------------------------------------------------------------
__global__ __launch_bounds__(256) void wcvt_kernel(
    const float* __restrict__ Wq, const float* __restrict__ Wk,
    const float* __restrict__ Wv, unsigned short* __restrict__ wt)
{
    __shared__ float lds[64][68];
    const int bid = (int)blockIdx.x;
    const int m = bid >> 4, kt = bid & 15, k0 = kt * 64;
    const float* W = (m == 0) ? Wq : (m == 1) ? Wk : Wv;
    const int t = (int)threadIdx.x;
#pragma unroll
    for (int j = 0; j < 4; j++) {
        int idx4 = j * 256 + t;
        int row = idx4 >> 4, c4 = idx4 & 15;
        float4 v = *(const float4*)(W + (size_t)(k0 + row) * 64 + c4 * 4);
        *(float4*)&lds[row][c4 * 4] = v;
    }
    __syncthreads();
#pragma unroll
    for (int j = 0; j < 2; j++) {
        int g = j * 256 + t;
        int n = g >> 3, kk = (g & 7) * 8;
        unsigned int o[4];
#pragma unroll
        for (int i = 0; i < 4; i++)
            o[i] = pack_bf2(lds[kk + 2 * i][n], lds[kk + 2 * i + 1][n]);
        *(uint4*)(wt + (size_t)(m * 64 + n) * 1024 + k0 + kk) =
            make_uint4(o[0], o[1], o[2], o[3]);
    }
}

// ---------------------------------------------------------------------------
// QKV: M=16384, N=192, K=1024. Grid (512 rowtiles), 512 thr (8 waves).
// Block: 32 rows x 192 cols (X read ONCE). Wave w: rows (w&1)*16,
// cols (w>>1)*48 (3 tiles). LDS 64 KB -> 2 blocks/CU = 4 waves/SIMD.
// ---------------------------------------------------------------------------
__global__ __launch_bounds__(512, 4) void qkv_kernel(
    const float* __restrict__ X, const unsigned short* __restrict__ wt,
    unsigned short* __restrict__ qg, unsigned short* __restrict__ kg,
    unsigned short* __restrict__ vtile)
{
    // layout: X dbuf 2x8 KB | W dbuf 2x24 KB
    __shared__ __align__(16) unsigned char smem[2 * 8192 + 2 * 24576];
    unsigned short* vstage = (unsigned short*)smem;   // 5 KB alias, post-loop

    const int t = (int)threadIdx.x;
    const int w = t >> 6, lane = t & 63;
    const int l15 = lane & 15, quad = lane >> 4;
    const int r0 = (int)blockIdx.x * 32;
    const int rbase = (w & 1) * 16;
    const int nloc0 = (w >> 1) * 48;   // colgroup 0..3

    const int wrow_off = lane >> 3, wgs = lane & 7;

    floatx4 acc[3];
#pragma unroll
    for (int j = 0; j < 3; j++) acc[j] = (floatx4){0.f, 0.f, 0.f, 0.f};

#define XBUF(q) (smem + (q) * 8192)
#define WBUF(q) (smem + 16384 + (q) * 24576)
    // X: 512 granules/chunk (32 rows x 16); wave w: gi = w*64 + lane (1 DMA)
#define STAGE_X(c, q) do {                                                   \
        const int gi = w * 64 + lane;                                        \
        const int row = gi >> 4;                                             \
        const int g = (gi & 15) ^ (row & 15);                                \
        load_lds16(X + (size_t)(r0 + row) * E_ + (c) * 64 + g * 4,           \
                   XBUF(q) + (w * 64) * 16);                                 \
    } while (0)
    // W: 192 rows x 8 granules; 24 regions of 8 rows; wave w: regions w*3+j
#define STAGE_W(c, q) do {                                                   \
        _Pragma("unroll")                                                    \
        for (int j = 0; j < 3; j++) {                                        \
            const int region = w * 3 + j;                                    \
            const int nloc = region * 8 + wrow_off;                          \
            const int gsrc = wgs ^ (nloc & 7);                               \
            load_lds16(wt + (size_t)nloc * 1024 + (c) * 64 + gsrc * 8,       \
                       WBUF(q) + region * 1024);                             \
        }                                                                    \
    } while (0)

    STAGE_X(0, 0);
    STAGE_W(0, 0);

#pragma unroll
    for (int c = 0; c < 16; c++) {
        __syncthreads();   // drains DMA issued last iter (vmcnt(0) structural)
        if (c + 1 < 16) {
            STAGE_X(c + 1, (c + 1) & 1);
            STAGE_W(c + 1, (c + 1) & 1);
        }
        const float4* xc = (const float4*)XBUF(c & 1);
        const unsigned short* wc = (const unsigned short*)WBUF(c & 1);

#pragma unroll
        for (int ks = 0; ks < 2; ks++) {
            const int g0 = ks * 8 + quad * 2;
            const float4* xrow = xc + (rbase + l15) * 16;
            float4 f0 = xrow[g0 ^ l15];
            float4 f1 = xrow[(g0 + 1) ^ l15];
            BF8 a;
            a.u[0] = pack_bf2(f0.x, f0.y);
            a.u[1] = pack_bf2(f0.z, f0.w);
            a.u[2] = pack_bf2(f1.x, f1.y);
            a.u[3] = pack_bf2(f1.z, f1.w);
#pragma unroll
            for (int nt = 0; nt < 3; nt++) {
                const int nloc = nloc0 + nt * 16 + l15;
                const int slot = (ks * 4 + quad) ^ (nloc & 7);
                short8 bfr = *(const short8*)(wc + nloc * 64 + slot * 8);
                acc[nt] = __builtin_amdgcn_mfma_f32_16x16x32_bf16(
                    a.s8, bfr, acc[nt], 0, 0, 0);
            }
        }
    }
#undef STAGE_X
#undef STAGE_W
#undef XBUF
#undef WBUF

    // epilogue (C/D: row = rbase + quad*4 + r, col n = nloc0 + nt*16 + l15)
    const int bb = r0 >> 11;
    const int keybase = r0 & 2047;
    const int rowl0 = rbase + quad * 4;
    __syncthreads();   // all LDS reads done; safe to alias vstage
#pragma unroll
    for (int nt = 0; nt < 3; nt++) {
        const int n = nloc0 + nt * 16 + l15;
        if (n < 64) {
#pragma unroll
            for (int r = 0; r < 4; r++)
                qg[(size_t)(r0 + rowl0 + r) * 64 + n] = f2bf(acc[nt][r] * SCALE);
        } else if (n < 128) {
#pragma unroll
            for (int r = 0; r < 4; r++)
                kg[(size_t)(r0 + rowl0 + r) * 64 + (n - 64)] = f2bf(acc[nt][r]);
        } else {
            const int h = n - 128;
            *(unsigned int*)&vstage[h * 40 + rowl0] =
                pack_bf2(acc[nt][0], acc[nt][1]);
            *(unsigned int*)&vstage[h * 40 + rowl0 + 2] =
                pack_bf2(acc[nt][2], acc[nt][3]);
        }
    }
    __syncthreads();
    // V tile: 64 h x 32 keys -> vtile[b][kb][h][64key]; 256 items
    if (t < 256) {
        const int h = t >> 2, part = t & 3;
        uint4 v = *(const uint4*)&vstage[h * 40 + part * 8];
        *(uint4*)(vtile + ((size_t)(bb * 32 + (keybase >> 6)) * 64 + h) * 64
                  + (keybase & 63) + part * 8) = v;
    }
}

// ---------------------------------------------------------------------------
// Attention split-K. Grid (8, 32, 4); 256 thr (4 waves); 64 q-rows/block.
// Split z covers key-tiles [8z, min(8z+8,nkt)). K/V dbuf via swizzled DMA.
// q0<512 (ns==1): direct normalized out. Else unnormalized partials. [R10]
// ---------------------------------------------------------------------------
__global__ __launch_bounds__(256, 3) void attn_kernel(
    const unsigned short* __restrict__ qg, const unsigned short* __restrict__ kg,
    const unsigned short* __restrict__ vtile, const int* __restrict__ zmask,
    float* __restrict__ opart, float* __restrict__ lpart,
    float* __restrict__ out)
{
    __shared__ unsigned short Klds[2][64 * 64];  // swizzled [key][64h]
    __shared__ unsigned short Vlds[2][64 * 64];  // swizzled [h][64key]
    __shared__ unsigned short Ps[64 * 88];       // per-wave-private rows

    const int t = (int)threadIdx.x;
    const int w = t >> 6, lane = t & 63;
    const int l15 = lane & 15, quad = lane >> 4;
    const int b = (int)blockIdx.x;
    const int qt = (int)blockIdx.y;            // 64-row q-tile, 0..31
    const int z = (int)blockIdx.z;
    const int q0 = qt * 64;
    const int nkt = qt + 1;                    // key-tiles needed (causal)
    const int t0 = z * 8;
    const int t1 = (t0 + 8 < nkt) ? (t0 + 8) : nkt;
    if (t0 >= t1) return;
    const int ns = (nkt + 7) >> 3;

    const int qlo = q0 + w * 16;
    const int myrow = qlo + quad * 4;
    const int srow_off = lane >> 3, sgs = lane & 7;

    short8 qfr[2];
#pragma unroll
    for (int kc = 0; kc < 2; kc++)
        qfr[kc] = *(const short8*)(qg + ((size_t)b * C_ + qlo + l15) * 64
                                   + kc * 32 + quad * 8);

    floatx4 accO[4];
#pragma unroll
    for (int i = 0; i < 4; i++) accO[i] = (floatx4){0.f, 0.f, 0.f, 0.f};
    float lsum[4] = {0.f, 0.f, 0.f, 0.f};

    // stage tile t0 into buf 0 (8 regions of 8 rows; wave w: regions 2w,2w+1)
#pragma unroll
    for (int j = 0; j < 2; j++) {
        const int region = w * 2 + j;
        const int row = region * 8 + srow_off;
        const int gsrc = sgs ^ (row & 7);
        load_lds16(kg + ((size_t)b * C_ + t0 * 64 + row) * 64 + gsrc * 8,
                   &Klds[0][region * 512]);
        load_lds16(vtile + (((size_t)b * 32 + t0) * 64 + row) * 64 + gsrc * 8,
                   &Vlds[0][region * 512]);
    }

    int buf = 0;
    for (int kt = t0; kt < t1; kt++) {
        __syncthreads();
        if (kt + 1 < t1) {
            const int k0n = (kt + 1) * 64;
#pragma unroll
            for (int j = 0; j < 2; j++) {
                const int region = w * 2 + j;
                const int row = region * 8 + srow_off;
                const int gsrc = sgs ^ (row & 7);
                load_lds16(kg + ((size_t)b * C_ + k0n + row) * 64 + gsrc * 8,
                           &Klds[buf ^ 1][region * 512]);
                load_lds16(vtile + (((size_t)b * 32 + kt + 1) * 64 + row) * 64 + gsrc * 8,
                           &Vlds[buf ^ 1][region * 512]);
            }
        }

        floatx4 s[4];
#pragma unroll
        for (int nt = 0; nt < 4; nt++) {
            const int row = nt * 16 + l15;
            short8 kf0 = *(const short8*)&Klds[buf][row * 64 + ((quad) ^ (row & 7)) * 8];
            short8 kf1 = *(const short8*)&Klds[buf][row * 64 + ((4 + quad) ^ (row & 7)) * 8];
            floatx4 zz = (floatx4){0.f, 0.f, 0.f, 0.f};
            zz = __builtin_amdgcn_mfma_f32_16x16x32_bf16(qfr[0], kf0, zz, 0, 0, 0);
            s[nt] = __builtin_amdgcn_mfma_f32_16x16x32_bf16(qfr[1], kf1, zz, 0, 0, 0);
        }
        float pr[4][4];
#pragma unroll
        for (int nt = 0; nt < 4; nt++)
#pragma unroll
            for (int r = 0; r < 4; r++)
                pr[nt][r] = __builtin_amdgcn_exp2f(s[nt][r]);
        if (kt == nkt - 1) {   // diagonal tile (only in last split)
            const int k0 = kt * 64;
#pragma unroll
            for (int nt = 0; nt < 4; nt++) {
                const int key = k0 + nt * 16 + l15;
#pragma unroll
                for (int r = 0; r < 4; r++)
                    if (key > myrow + r) pr[nt][r] = 0.f;
            }
        }
#pragma unroll
        for (int nt = 0; nt < 4; nt++)
#pragma unroll
            for (int r = 0; r < 4; r++) {
                lsum[r] += pr[nt][r];
                Ps[(w * 16 + quad * 4 + r) * 88 + nt * 16 + l15] = f2bf(pr[nt][r]);
            }
#pragma unroll
        for (int kc = 0; kc < 2; kc++) {
            short8 af = *(const short8*)&Ps[(w * 16 + l15) * 88 + kc * 32 + quad * 8];
#pragma unroll
            for (int nt = 0; nt < 4; nt++) {
                const int row = nt * 16 + l15;
                short8 vf = *(const short8*)&Vlds[buf][row * 64
                                + ((kc * 4 + quad) ^ (row & 7)) * 8];
                accO[nt] = __builtin_amdgcn_mfma_f32_16x16x32_bf16(
                    af, vf, accO[nt], 0, 0, 0);
            }
        }
        buf ^= 1;
    }

    // reduce l across the 16 col-lanes
#pragma unroll
    for (int r = 0; r < 4; r++) {
        float v = lsum[r];
        v += __shfl_xor(v, 1);
        v += __shfl_xor(v, 2);
        v += __shfl_xor(v, 4);
        v += __shfl_xor(v, 8);
        lsum[r] = v;
    }

    if (ns == 1) {
        float inv[4];
#pragma unroll
        for (int r = 0; r < 4; r++) {
            int zm = zmask[b * C_ + myrow + r];
            inv[r] = zm ? 0.f : 1.0f / lsum[r];
        }
#pragma unroll
        for (int nt = 0; nt < 4; nt++)
#pragma unroll
            for (int r = 0; r < 4; r++)
                out[(size_t)(b * C_ + myrow + r) * 64 + nt * 16 + l15] =
                    accO[nt][r] * inv[r];
    } else {
        // partials (myrow >= 512): opart[z][b][row-512][h]
        const int lrow = myrow - 512;
        float* ob = opart + ((size_t)(z * 8 + b) * 1536 + lrow) * 64;
#pragma unroll
        for (int nt = 0; nt < 4; nt++)
#pragma unroll
            for (int r = 0; r < 4; r++)
                ob[(size_t)r * 64 + nt * 16 + l15] = accO[nt][r];
        if (l15 == 0) {
#pragma unroll
            for (int r = 0; r < 4; r++)
                lpart[(size_t)(z * 8 + b) * 1536 + lrow + r] = lsum[r];
        }
    }
}

// ---------------------------------------------------------------------------
// Combine rows >= 512: out = sum_z O_z / sum_z l_z, zmask applied.
// Grid (96, 8): 8 b x 1536 rows x 16 float4.                    [R10 verbatim]
// ---------------------------------------------------------------------------
__global__ __launch_bounds__(256) void combine_kernel(
    const float* __restrict__ opart, const float* __restrict__ lpart,
    const int* __restrict__ zmask, float* __restrict__ out)
{
    const int b = (int)blockIdx.y;
    const int gid = (int)blockIdx.x * 256 + (int)threadIdx.x;  // 0..24575
    const int lrow = gid >> 4;         // 0..1535
    const int f4 = gid & 15;
    const int row = 512 + lrow;
    const int nkt = (row >> 6) + 1;
    const int ns = (nkt + 7) >> 3;     // 2..4

    float4 o = make_float4(0.f, 0.f, 0.f, 0.f);
    float l = 0.f;
    for (int zc = 0; zc < ns; zc++) {
        float4 p = *(const float4*)(opart
            + ((size_t)(zc * 8 + b) * 1536 + lrow) * 64 + f4 * 4);
        o.x += p.x; o.y += p.y; o.z += p.z; o.w += p.w;
        l += lpart[(size_t)(zc * 8 + b) * 1536 + lrow];
    }
    const float inv = zmask[b * C_ + row] ? 0.f : 1.0f / l;
    *(float4*)(out + (size_t)(b * C_ + row) * 64 + f4 * 4) =
        make_float4(o.x * inv, o.y * inv, o.z * inv, o.w * inv);
}

// ---------------------------------------------------------------------------
extern "C" void kernel_launch(void* const* d_in, const int* in_sizes, int n_in,
                              void* d_out, int out_size, void* d_ws, size_t ws_size,
                              hipStream_t stream) {
    const float* X  = (const float*)d_in[0];
    const float* Wq = (const float*)d_in[1];
    const float* Wk = (const float*)d_in[2];
    const float* Wv = (const float*)d_in[3];
    const int*   zm = (const int*)d_in[4];
    float* out = (float*)d_out;

    unsigned short* qg    = (unsigned short*)d_ws;               // 2 MB
    unsigned short* kg    = qg    + (size_t)B_ * C_ * H_;        // 2 MB
    unsigned short* vtile = kg    + (size_t)B_ * C_ * H_;        // 2 MB
    unsigned short* wt    = vtile + (size_t)B_ * C_ * H_;        // 384 KB
    float* opart = (float*)(wt + (size_t)192 * 1024);            // 12.6 MB
    float* lpart = opart + (size_t)4 * 8 * 1536 * 64;            // 192 KB

    wcvt_kernel<<<dim3(48), dim3(256), 0, stream>>>(Wq, Wk, Wv, wt);
    qkv_kernel<<<dim3(512), dim3(512), 0, stream>>>(X, wt, qg, kg, vtile);
    attn_kernel<<<dim3(B_, 32, 4), dim3(256), 0, stream>>>(
        qg, kg, vtile, zm, opart, lpart, out);
    combine_kernel<<<dim3(96, B_), dim3(256), 0, stream>>>(opart, lpart, zm, out);
}

// Round 8
// 132.483 us; speedup vs baseline: 1.0750x; 1.0174x over previous
//
#include <hip/hip_runtime.h>
#include <math.h>

// Single-head causal attention, MFMA bf16 pipeline (R17 = R10 + 64-row qkv).
//   x:[8,2048,1024] f32, Wq/Wk/Wv:[1024,64] f32, zero_mask:[8,2048] i32
//   out:[8,2048,64] f32
// R15/R16 post-mortem: qkv is bound by aggregate STAGED traffic into LDS
// (X 64 MB + W re-read 512x384KB = 196 MB = 260 MB at ~6.2 TB/s = 42 us),
// not latency/occupancy. R17 halves W re-reads: 64-row x 192-col blocks
// (256 blocks): staged bytes 260 -> 162 MB. X is reg-staged + converted to
// bf16 BEFORE LDS (8 KB/buf; inner loop reads A-frags via ds_read_b128
// directly -- no float4 reads, no packs). W DMA dbuf 48 KB. LDS 64 KB.
//
// wcvt: Wt[192][1024] bf16 (B-operand layout)                       [R10]
// qkv : 256 blocks x 512 thr (8 waves), 64 rows x 192 cols, single X pass.
//       Wave w: rows (w&3)*16, cols (w>>2)*96 (6 tiles). One barrier/chunk.
// attn: R10 verbatim (64 q-rows, 4 waves, dbuf K/V swizzled DMA, Ps
//       stride-88, split-K chunk 8, grid (8,32,4)).
// comb: rows >= 512 sum ns=ceil(nkt/8) in {2..4} partials.          [R10]
//
// MFMA 16x16x32 layouts (HW-verified):
//   A[m][k]: m = lane&15, k = (lane>>4)*8 + j
//   B[k][n]: n = lane&15, k = (lane>>4)*8 + j
//   C/D:     col = lane&15, row = (lane>>4)*4 + reg
//
// Swizzles (reader applies same XOR as the writer permutation):
//   W row (64 bf16 = 8 granules):  slot = g ^ (nloc & 7)   [DMA src-swizzled]
//   X row (64 bf16 = 8 granules):  slot = g ^ (row & 7)    [ds_write-swizzled]

#define B_ 8
#define C_ 2048
#define E_ 1024
#define H_ 64
// 2048^-0.5 * log2(e): scores are computed in the log2 domain -> v_exp_f32
#define SCALE (0.02209708691207961f * 1.4426950408889634f)

typedef __attribute__((ext_vector_type(8))) short short8;
typedef __attribute__((ext_vector_type(4))) float floatx4;

static __device__ __forceinline__ unsigned int pack_bf2(float lo, float hi) {
    unsigned int a = __builtin_bit_cast(unsigned int, lo);
    unsigned int b = __builtin_bit_cast(unsigned int, hi);
    return (a >> 16) | (b & 0xFFFF0000u);
}
static __device__ __forceinline__ unsigned short f2bf(float f) {
    return (unsigned short)(__builtin_bit_cast(unsigned int, f) >> 16);
}
static __device__ __forceinline__ void load_lds16(const void* g, void* l) {
    __builtin_amdgcn_global_load_lds(
        (const __attribute__((address_space(1))) void*)g,
        (__attribute__((address_space(3))) void*)l, 16, 0, 0);
}

// ---------------------------------------------------------------------------
// Wt[n=192][k=1024] bf16 from Wq/Wk/Wv[k][64] f32. 48 blocks.   [R10 verbatim]
// ---------------------------------------------------------------------------
__global__ __launch_bounds__(256) void wcvt_kernel(
    const float* __restrict__ Wq, const float* __restrict__ Wk,
    const float* __restrict__ Wv, unsigned short* __restrict__ wt)
{
    __shared__ float lds[64][68];
    const int bid = (int)blockIdx.x;
    const int m = bid >> 4, kt = bid & 15, k0 = kt * 64;
    const float* W = (m == 0) ? Wq : (m == 1) ? Wk : Wv;
    const int t = (int)threadIdx.x;
#pragma unroll
    for (int j = 0; j < 4; j++) {
        int idx4 = j * 256 + t;
        int row = idx4 >> 4, c4 = idx4 & 15;
        float4 v = *(const float4*)(W + (size_t)(k0 + row) * 64 + c4 * 4);
        *(float4*)&lds[row][c4 * 4] = v;
    }
    __syncthreads();
#pragma unroll
    for (int j = 0; j < 2; j++) {
        int g = j * 256 + t;
        int n = g >> 3, kk = (g & 7) * 8;
        unsigned int o[4];
#pragma unroll
        for (int i = 0; i < 4; i++)
            o[i] = pack_bf2(lds[kk + 2 * i][n], lds[kk + 2 * i + 1][n]);
        *(uint4*)(wt + (size_t)(m * 64 + n) * 1024 + k0 + kk) =
            make_uint4(o[0], o[1], o[2], o[3]);
    }
}

// ---------------------------------------------------------------------------
// QKV: M=16384, N=192, K=1024. Grid (256 rowtiles), 512 thr (8 waves).
// Block: 64 rows x 192 cols (X read once, W re-read halved vs R10).
// Wave w: rows (w&3)*16, cols (w>>2)*96 (6 tiles).
// LDS: X bf16 dbuf 2x8 KB (reg-staged, swizzled ds_write) +
//      W dbuf 2x24 KB (swizzled DMA) = 64 KB.
// ---------------------------------------------------------------------------
__global__ __launch_bounds__(512, 2) void qkv_kernel(
    const float* __restrict__ X, const unsigned short* __restrict__ wt,
    unsigned short* __restrict__ qg, unsigned short* __restrict__ kg,
    unsigned short* __restrict__ vtile)
{
    // layout: X bf16 dbuf 2x8 KB | W dbuf 2x24 KB
    __shared__ __align__(16) unsigned char smem[2 * 8192 + 2 * 24576];
    unsigned short* vstage = (unsigned short*)smem;  // 9 KB alias, post-loop

    const int t = (int)threadIdx.x;
    const int w = t >> 6, lane = t & 63;
    const int l15 = lane & 15, quad = lane >> 4;
    const int r0 = (int)blockIdx.x * 64;
    const int rbase = (w & 3) * 16;
    const int nloc0 = (w >> 2) * 96;

    const int wrow_off = lane >> 3, wgs = lane & 7;

    // X reg-staging assignment: thread t -> row xr = t>>3, granule xg = t&7
    const int xr = t >> 3;              // 0..63
    const int xg = t & 7;               // granule (8 bf16 = 16 B)
    const int xslot = xg ^ (xr & 7);    // swizzled LDS slot
    const float* xsrc = X + (size_t)(r0 + xr) * E_ + xg * 8;

    floatx4 acc[6];
#pragma unroll
    for (int j = 0; j < 6; j++) acc[j] = (floatx4){0.f, 0.f, 0.f, 0.f};

    float4 xa0, xa1;   // in-flight X chunk (8 f32)

#define XBUF(q) ((unsigned short*)(smem + (q) * 8192))
#define WBUF(q) ((unsigned short*)(smem + 16384 + (q) * 24576))
    // issue 8-f32 global load for chunk c (latency hidden under compute)
#define LOADX(c) do {                                                        \
        xa0 = *(const float4*)(xsrc + (size_t)(c) * 64);                     \
        xa1 = *(const float4*)(xsrc + (size_t)(c) * 64 + 4);                 \
    } while (0)
    // convert + swizzled ds_write into XBUF(q)
#define WRITEX(q) do {                                                       \
        uint4 o = make_uint4(pack_bf2(xa0.x, xa0.y), pack_bf2(xa0.z, xa0.w), \
                             pack_bf2(xa1.x, xa1.y), pack_bf2(xa1.z, xa1.w));\
        *(uint4*)(XBUF(q) + xr * 64 + xslot * 8) = o;                        \
    } while (0)
    // W: 192 rows x 8 granules; 24 regions of 8 rows; wave w: regions w*3+j
#define STAGE_W(c, q) do {                                                   \
        _Pragma("unroll")                                                    \
        for (int j = 0; j < 3; j++) {                                        \
            const int region = w * 3 + j;                                    \
            const int nloc = region * 8 + wrow_off;                          \
            const int gsrc = wgs ^ (nloc & 7);                               \
            load_lds16(wt + (size_t)nloc * 1024 + (c) * 64 + gsrc * 8,       \
                       (unsigned char*)WBUF(q) + region * 1024);             \
        }                                                                    \
    } while (0)

    // prologue: chunk 0 into buffer 0
    LOADX(0);
    STAGE_W(0, 0);
    WRITEX(0);
    __syncthreads();   // drains W DMA + X ds_writes for chunk 0

#pragma unroll
    for (int c = 0; c < 16; c++) {
        if (c + 1 < 16) {
            LOADX(c + 1);                  // issue early: lands under compute
            STAGE_W(c + 1, (c + 1) & 1);   // DMA into other buffer
        }
        const unsigned short* xc = XBUF(c & 1);
        const unsigned short* wc = WBUF(c & 1);
#pragma unroll
        for (int ks = 0; ks < 2; ks++) {
            const int arow = rbase + l15;
            short8 af = *(const short8*)(xc + arow * 64
                            + (((ks * 4 + quad) ^ (arow & 7)) * 8));
#pragma unroll
            for (int nt = 0; nt < 6; nt++) {
                const int nloc = nloc0 + nt * 16 + l15;
                const int slot = (ks * 4 + quad) ^ (nloc & 7);
                short8 bfr = *(const short8*)(wc + nloc * 64 + slot * 8);
                acc[nt] = __builtin_amdgcn_mfma_f32_16x16x32_bf16(
                    af, bfr, acc[nt], 0, 0, 0);
            }
        }
        if (c + 1 < 16) WRITEX((c + 1) & 1);   // cvt + ds_write (other buffer)
        __syncthreads();   // all readers done; chunk c+1 fully staged
    }
#undef LOADX
#undef WRITEX
#undef STAGE_W
#undef XBUF
#undef WBUF

    // epilogue (C/D: local row = rbase + quad*4 + r, col n = nloc0+nt*16+l15)
    const int bb = r0 >> 11;
    const int kb = (r0 >> 6) & 31;
    const int keyl = rbase + quad * 4;   // local key index 0..63
    // vstage[h][key]: 64 x 72 ushort (9216 B), aliases XBUF -- safe after
    // the final loop barrier.
#pragma unroll
    for (int nt = 0; nt < 6; nt++) {
        const int n = nloc0 + nt * 16 + l15;
        if (n < 64) {
#pragma unroll
            for (int r = 0; r < 4; r++)
                qg[(size_t)(r0 + keyl + r) * 64 + n] = f2bf(acc[nt][r] * SCALE);
        } else if (n < 128) {
#pragma unroll
            for (int r = 0; r < 4; r++)
                kg[(size_t)(r0 + keyl + r) * 64 + (n - 64)] = f2bf(acc[nt][r]);
        } else {
            const int h = n - 128;
            *(unsigned int*)&vstage[h * 72 + keyl] =
                pack_bf2(acc[nt][0], acc[nt][1]);
            *(unsigned int*)&vstage[h * 72 + keyl + 2] =
                pack_bf2(acc[nt][2], acc[nt][3]);
        }
    }
    __syncthreads();
    // V tile: 64 h x 64 keys -> vtile[b][kb][h][64key]; 512 x uint4
    {
        const int h = t >> 3, part = t & 7;
        uint4 v = *(const uint4*)&vstage[h * 72 + part * 8];
        *(uint4*)(vtile + ((size_t)(bb * 32 + kb) * 64 + h) * 64 + part * 8) = v;
    }
}

// ---------------------------------------------------------------------------
// Attention split-K. Grid (8, 32, 4); 256 thr (4 waves); 64 q-rows/block.
// Split z covers key-tiles [8z, min(8z+8,nkt)). K/V dbuf via swizzled DMA.
// q0<512 (ns==1): direct normalized out. Else unnormalized partials. [R10]
// ---------------------------------------------------------------------------
__global__ __launch_bounds__(256, 3) void attn_kernel(
    const unsigned short* __restrict__ qg, const unsigned short* __restrict__ kg,
    const unsigned short* __restrict__ vtile, const int* __restrict__ zmask,
    float* __restrict__ opart, float* __restrict__ lpart,
    float* __restrict__ out)
{
    __shared__ unsigned short Klds[2][64 * 64];  // swizzled [key][64h]
    __shared__ unsigned short Vlds[2][64 * 64];  // swizzled [h][64key]
    __shared__ unsigned short Ps[64 * 88];       // per-wave-private rows

    const int t = (int)threadIdx.x;
    const int w = t >> 6, lane = t & 63;
    const int l15 = lane & 15, quad = lane >> 4;
    const int b = (int)blockIdx.x;
    const int qt = (int)blockIdx.y;            // 64-row q-tile, 0..31
    const int z = (int)blockIdx.z;
    const int q0 = qt * 64;
    const int nkt = qt + 1;                    // key-tiles needed (causal)
    const int t0 = z * 8;
    const int t1 = (t0 + 8 < nkt) ? (t0 + 8) : nkt;
    if (t0 >= t1) return;
    const int ns = (nkt + 7) >> 3;

    const int qlo = q0 + w * 16;
    const int myrow = qlo + quad * 4;
    const int srow_off = lane >> 3, sgs = lane & 7;

    short8 qfr[2];
#pragma unroll
    for (int kc = 0; kc < 2; kc++)
        qfr[kc] = *(const short8*)(qg + ((size_t)b * C_ + qlo + l15) * 64
                                   + kc * 32 + quad * 8);

    floatx4 accO[4];
#pragma unroll
    for (int i = 0; i < 4; i++) accO[i] = (floatx4){0.f, 0.f, 0.f, 0.f};
    float lsum[4] = {0.f, 0.f, 0.f, 0.f};

    // stage tile t0 into buf 0 (8 regions of 8 rows; wave w: regions 2w,2w+1)
#pragma unroll
    for (int j = 0; j < 2; j++) {
        const int region = w * 2 + j;
        const int row = region * 8 + srow_off;
        const int gsrc = sgs ^ (row & 7);
        load_lds16(kg + ((size_t)b * C_ + t0 * 64 + row) * 64 + gsrc * 8,
                   &Klds[0][region * 512]);
        load_lds16(vtile + (((size_t)b * 32 + t0) * 64 + row) * 64 + gsrc * 8,
                   &Vlds[0][region * 512]);
    }

    int buf = 0;
    for (int kt = t0; kt < t1; kt++) {
        __syncthreads();
        if (kt + 1 < t1) {
            const int k0n = (kt + 1) * 64;
#pragma unroll
            for (int j = 0; j < 2; j++) {
                const int region = w * 2 + j;
                const int row = region * 8 + srow_off;
                const int gsrc = sgs ^ (row & 7);
                load_lds16(kg + ((size_t)b * C_ + k0n + row) * 64 + gsrc * 8,
                           &Klds[buf ^ 1][region * 512]);
                load_lds16(vtile + (((size_t)b * 32 + kt + 1) * 64 + row) * 64 + gsrc * 8,
                           &Vlds[buf ^ 1][region * 512]);
            }
        }

        floatx4 s[4];
#pragma unroll
        for (int nt = 0; nt < 4; nt++) {
            const int row = nt * 16 + l15;
            short8 kf0 = *(const short8*)&Klds[buf][row * 64 + ((quad) ^ (row & 7)) * 8];
            short8 kf1 = *(const short8*)&Klds[buf][row * 64 + ((4 + quad) ^ (row & 7)) * 8];
            floatx4 zz = (floatx4){0.f, 0.f, 0.f, 0.f};
            zz = __builtin_amdgcn_mfma_f32_16x16x32_bf16(qfr[0], kf0, zz, 0, 0, 0);
            s[nt] = __builtin_amdgcn_mfma_f32_16x16x32_bf16(qfr[1], kf1, zz, 0, 0, 0);
        }
        float pr[4][4];
#pragma unroll
        for (int nt = 0; nt < 4; nt++)
#pragma unroll
            for (int r = 0; r < 4; r++)
                pr[nt][r] = __builtin_amdgcn_exp2f(s[nt][r]);
        if (kt == nkt - 1) {   // diagonal tile (only in last split)
            const int k0 = kt * 64;
#pragma unroll
            for (int nt = 0; nt < 4; nt++) {
                const int key = k0 + nt * 16 + l15;
#pragma unroll
                for (int r = 0; r < 4; r++)
                    if (key > myrow + r) pr[nt][r] = 0.f;
            }
        }
#pragma unroll
        for (int nt = 0; nt < 4; nt++)
#pragma unroll
            for (int r = 0; r < 4; r++) {
                lsum[r] += pr[nt][r];
                Ps[(w * 16 + quad * 4 + r) * 88 + nt * 16 + l15] = f2bf(pr[nt][r]);
            }
#pragma unroll
        for (int kc = 0; kc < 2; kc++) {
            short8 af = *(const short8*)&Ps[(w * 16 + l15) * 88 + kc * 32 + quad * 8];
#pragma unroll
            for (int nt = 0; nt < 4; nt++) {
                const int row = nt * 16 + l15;
                short8 vf = *(const short8*)&Vlds[buf][row * 64
                                + ((kc * 4 + quad) ^ (row & 7)) * 8];
                accO[nt] = __builtin_amdgcn_mfma_f32_16x16x32_bf16(
                    af, vf, accO[nt], 0, 0, 0);
            }
        }
        buf ^= 1;
    }

    // reduce l across the 16 col-lanes
#pragma unroll
    for (int r = 0; r < 4; r++) {
        float v = lsum[r];
        v += __shfl_xor(v, 1);
        v += __shfl_xor(v, 2);
        v += __shfl_xor(v, 4);
        v += __shfl_xor(v, 8);
        lsum[r] = v;
    }

    if (ns == 1) {
        float inv[4];
#pragma unroll
        for (int r = 0; r < 4; r++) {
            int zm = zmask[b * C_ + myrow + r];
            inv[r] = zm ? 0.f : 1.0f / lsum[r];
        }
#pragma unroll
        for (int nt = 0; nt < 4; nt++)
#pragma unroll
            for (int r = 0; r < 4; r++)
                out[(size_t)(b * C_ + myrow + r) * 64 + nt * 16 + l15] =
                    accO[nt][r] * inv[r];
    } else {
        // partials (myrow >= 512): opart[z][b][row-512][h]
        const int lrow = myrow - 512;
        float* ob = opart + ((size_t)(z * 8 + b) * 1536 + lrow) * 64;
#pragma unroll
        for (int nt = 0; nt < 4; nt++)
#pragma unroll
            for (int r = 0; r < 4; r++)
                ob[(size_t)r * 64 + nt * 16 + l15] = accO[nt][r];
        if (l15 == 0) {
#pragma unroll
            for (int r = 0; r < 4; r++)
                lpart[(size_t)(z * 8 + b) * 1536 + lrow + r] = lsum[r];
        }
    }
}

// ---------------------------------------------------------------------------
// Combine rows >= 512: out = sum_z O_z / sum_z l_z, zmask applied.
// Grid (96, 8): 8 b x 1536 rows x 16 float4.                    [R10 verbatim]
// ---------------------------------------------------------------------------
__global__ __launch_bounds__(256) void combine_kernel(
    const float* __restrict__ opart, const float* __restrict__ lpart,
    const int* __restrict__ zmask, float* __restrict__ out)
{
    const int b = (int)blockIdx.y;
    const int gid = (int)blockIdx.x * 256 + (int)threadIdx.x;  // 0..24575
    const int lrow = gid >> 4;         // 0..1535
    const int f4 = gid & 15;
    const int row = 512 + lrow;
    const int nkt = (row >> 6) + 1;
    const int ns = (nkt + 7) >> 3;     // 2..4

    float4 o = make_float4(0.f, 0.f, 0.f, 0.f);
    float l = 0.f;
    for (int zc = 0; zc < ns; zc++) {
        float4 p = *(const float4*)(opart
            + ((size_t)(zc * 8 + b) * 1536 + lrow) * 64 + f4 * 4);
        o.x += p.x; o.y += p.y; o.z += p.z; o.w += p.w;
        l += lpart[(size_t)(zc * 8 + b) * 1536 + lrow];
    }
    const float inv = zmask[b * C_ + row] ? 0.f : 1.0f / l;
    *(float4*)(out + (size_t)(b * C_ + row) * 64 + f4 * 4) =
        make_float4(o.x * inv, o.y * inv, o.z * inv, o.w * inv);
}

// ---------------------------------------------------------------------------
extern "C" void kernel_launch(void* const* d_in, const int* in_sizes, int n_in,
                              void* d_out, int out_size, void* d_ws, size_t ws_size,
                              hipStream_t stream) {
    const float* X  = (const float*)d_in[0];
    const float* Wq = (const float*)d_in[1];
    const float* Wk = (const float*)d_in[2];
    const float* Wv = (const float*)d_in[3];
    const int*   zm = (const int*)d_in[4];
    float* out = (float*)d_out;

    unsigned short* qg    = (unsigned short*)d_ws;               // 2 MB
    unsigned short* kg    = qg    + (size_t)B_ * C_ * H_;        // 2 MB
    unsigned short* vtile = kg    + (size_t)B_ * C_ * H_;        // 2 MB
    unsigned short* wt    = vtile + (size_t)B_ * C_ * H_;        // 384 KB
    float* opart = (float*)(wt + (size_t)192 * 1024);            // 12.6 MB
    float* lpart = opart + (size_t)4 * 8 * 1536 * 64;            // 192 KB

    wcvt_kernel<<<dim3(48), dim3(256), 0, stream>>>(Wq, Wk, Wv, wt);
    qkv_kernel<<<dim3(256), dim3(512), 0, stream>>>(X, wt, qg, kg, vtile);
    attn_kernel<<<dim3(B_, 32, 4), dim3(256), 0, stream>>>(
        qg, kg, vtile, zm, opart, lpart, out);
    combine_kernel<<<dim3(96, B_), dim3(256), 0, stream>>>(opart, lpart, zm, out);
}